// Round 9
// baseline (132.396 us; speedup 1.0000x reference)
//
#include <hip/hip_runtime.h>
#include <hip/hip_bf16.h>

typedef __attribute__((ext_vector_type(8))) short s16x8;
typedef __attribute__((ext_vector_type(4))) float f32x4;
typedef __attribute__((ext_vector_type(16))) float f32x16;
typedef __attribute__((ext_vector_type(2))) unsigned int u32x2;
typedef __attribute__((ext_vector_type(4))) unsigned int u32x4;

#define MFMA16(a, b, c) __builtin_amdgcn_mfma_f32_16x16x32_bf16((a), (b), (c), 0, 0, 0)
#define MFMA32(a, b, c) __builtin_amdgcn_mfma_f32_32x32x16_bf16((a), (b), (c), 0, 0, 0)
#define LOG2E 1.4426950408889634f

static __device__ __forceinline__ unsigned int pk2(float a, float b) {
  union { __hip_bfloat162 h2; unsigned int u; } cv;
  cv.h2 = __float22bfloat162_rn(make_float2(a, b));
  return cv.u;
}
static __device__ __forceinline__ int div7(int x) { return (x * 9363) >> 16; }  // exact 0..62
static __device__ __forceinline__ int swz256(int row, int byteoff) {
  return row * 256 + (byteoff ^ ((row & 7) << 4));
}
static __device__ __forceinline__ int swz128(int row, int byteoff) {
  return row * 128 + (byteoff ^ ((row & 7) << 4));
}
static __device__ __forceinline__ void gload16(const void* g, void* l) {
  __builtin_amdgcn_global_load_lds(
      (const __attribute__((address_space(1))) unsigned int*)g,
      (__attribute__((address_space(3))) unsigned int*)l, 16, 0, 0);
}

// ---------- prep: weights fp32->bf16 ; rpbm[case][head][64][64] = (rpb + mask)*log2e ----------
__global__ void swin_prep(const float* __restrict__ wq, const float* __restrict__ wk,
                          const float* __restrict__ wv, const float* __restrict__ wp,
                          const float* __restrict__ rpb_table,
                          unsigned short* __restrict__ wsW, float* __restrict__ rpbm) {
  int idx = blockIdx.x * 256 + threadIdx.x;
  if (idx < 65536) {
    int t = idx >> 14, loc = idx & 16383;
    const float* s = (t == 0) ? wq : (t == 1) ? wk : (t == 2) ? wv : wp;
    union { __hip_bfloat16 h; unsigned short u; } cv;
    cv.h = __float2bfloat16(s[loc]);
    wsW[idx] = cv.u;
  } else {
    int k = idx - 65536;               // [case(2b)][head(2b)][i(6b)][j(6b)]
    int c = k >> 14;
    int h = (k >> 12) & 3;
    int i = (k >> 6) & 63, j = k & 63;
    float val;
    if (j >= 49) val = -1e30f;
    else if (i >= 49) val = 0.f;
    else {
      int yi = div7(i), xi = i - yi * 7;
      int yj = div7(j), xj = j - yj * 7;
      int ridx = (yi - yj + 6) * 13 + (xi - xj + 6);
      val = rpb_table[ridx * 4 + h];
      int cwi = c >> 1, cwj = c & 1;
      int rgi = (cwi ? (yi < 4 ? 3 : 6) : 0) + (cwj ? (xi < 4 ? 1 : 2) : 0);
      int rgj = (cwi ? (yj < 4 ? 3 : 6) : 0) + (cwj ? (xj < 4 ? 1 : 2) : 0);
      if (rgi != rgj) val -= 100.f;
      val *= LOG2E;
    }
    rpbm[k] = val;
  }
}

// ================= K1: QKV projection -> swizzled bf16 image in global =================
__global__ __launch_bounds__(512, 6) void swin_qkv(
    const float* __restrict__ xq, const float* __restrict__ xk, const float* __restrict__ xv,
    const float* __restrict__ bq, const float* __restrict__ bk, const float* __restrict__ bv,
    const unsigned short* __restrict__ wsW, char* __restrict__ qkvimg) {
  __shared__ __align__(16) char sm[49152];   // r0 Xq, r1 Xk, r2 Xv

  const int tid = threadIdx.x;
  const int lane = tid & 63;
  const int wv_ = tid >> 6;
  const int l15 = lane & 15;
  const int lg = lane >> 4;
  const int kgrp = lg * 8;
  const int rsub = lg * 4;

  const int bid = blockIdx.x;
  const int b = bid >> 6;
  const int widx = bid & 63;
  const int wi = widx >> 3, wj = widx & 7;
  const long obase = (long)b * 56 * 56 * 128;

  const int xrow = tid >> 3;
  const int xk16 = (tid & 7) << 4;
  long xoff = -1;
  if (xrow < 49) {
    int ty = div7(xrow), tx = xrow - ty * 7;
    int ih = wi * 7 + ty + 3; if (ih >= 56) ih -= 56;
    int iw = wj * 7 + tx + 3; if (iw >= 56) iw -= 56;
    xoff = obase + (long)((ih * 56 + iw) * 128 + xk16);
  }
  {
    float ra[16], rb[16], rc[16];
#pragma unroll
    for (int i = 0; i < 16; ++i) { ra[i] = 0.f; rb[i] = 0.f; rc[i] = 0.f; }
    if (xoff >= 0) {
#pragma unroll
      for (int q = 0; q < 4; ++q) {
        f32x4 v = *(const f32x4*)(xq + xoff + q * 4);
        ra[q*4+0]=v[0]; ra[q*4+1]=v[1]; ra[q*4+2]=v[2]; ra[q*4+3]=v[3];
      }
#pragma unroll
      for (int q = 0; q < 4; ++q) {
        f32x4 v = *(const f32x4*)(xk + xoff + q * 4);
        rb[q*4+0]=v[0]; rb[q*4+1]=v[1]; rb[q*4+2]=v[2]; rb[q*4+3]=v[3];
      }
#pragma unroll
      for (int q = 0; q < 4; ++q) {
        f32x4 v = *(const f32x4*)(xv + xoff + q * 4);
        rc[q*4+0]=v[0]; rc[q*4+1]=v[1]; rc[q*4+2]=v[2]; rc[q*4+3]=v[3];
      }
    }
    auto wrx = [&](int base, const float* r) {
      unsigned int w[8];
#pragma unroll
      for (int i = 0; i < 8; ++i) w[i] = pk2(r[2*i], r[2*i+1]);
      u32x4 a = {w[0], w[1], w[2], w[3]};
      u32x4 bb2 = {w[4], w[5], w[6], w[7]};
      *(u32x4*)(sm + base + swz256(xrow, xk16 * 2)) = a;
      *(u32x4*)(sm + base + swz256(xrow, xk16 * 2 + 16)) = bb2;
    };
    wrx(0, ra); wrx(16384, rb); wrx(32768, rc);
  }
  __syncthreads();

  const float QSCALE = 0.17677669529663687f * LOG2E;
  const long wb = (long)bid * 49152;
  const int nrow = wv_ * 16 + l15;
  {  // Q: D[n][tok], lane = token
    s16x8 afr[4];
#pragma unroll
    for (int kt = 0; kt < 4; ++kt)
      afr[kt] = *(const s16x8*)(wsW + nrow * 128 + kt * 32 + kgrp);
    f32x4 bv4 = *(const f32x4*)(bq + wv_ * 16 + rsub);
#pragma unroll
    for (int tt = 0; tt < 4; ++tt) {
      f32x4 acc = {0.f, 0.f, 0.f, 0.f};
#pragma unroll
      for (int kt = 0; kt < 4; ++kt) {
        s16x8 bfr = *(const s16x8*)(sm + swz256(tt * 16 + l15, (kt * 32 + kgrp) * 2));
        acc = MFMA16(afr[kt], bfr, acc);
      }
      u32x2 w = {pk2((acc[0] + bv4[0]) * QSCALE, (acc[1] + bv4[1]) * QSCALE),
                 pk2((acc[2] + bv4[2]) * QSCALE, (acc[3] + bv4[3]) * QSCALE)};
      *(u32x2*)(qkvimg + wb + swz256(tt * 16 + l15, 2 * (wv_ * 16 + rsub))) = w;
    }
  }
  {  // K
    s16x8 afr[4];
#pragma unroll
    for (int kt = 0; kt < 4; ++kt)
      afr[kt] = *(const s16x8*)(wsW + 16384 + nrow * 128 + kt * 32 + kgrp);
    f32x4 bv4 = *(const f32x4*)(bk + wv_ * 16 + rsub);
#pragma unroll
    for (int tt = 0; tt < 4; ++tt) {
      f32x4 acc = {0.f, 0.f, 0.f, 0.f};
#pragma unroll
      for (int kt = 0; kt < 4; ++kt) {
        s16x8 bfr = *(const s16x8*)(sm + 16384 + swz256(tt * 16 + l15, (kt * 32 + kgrp) * 2));
        acc = MFMA16(afr[kt], bfr, acc);
      }
      u32x2 w = {pk2(acc[0] + bv4[0], acc[1] + bv4[1]),
                 pk2(acc[2] + bv4[2], acc[3] + bv4[3])};
      *(u32x2*)(qkvimg + wb + 16384 + swz256(tt * 16 + l15, 2 * (wv_ * 16 + rsub))) = w;
    }
  }
  {  // V (lane = ch) -> V^T image [128 ch][64 tok]
    s16x8 bfrw[4];
#pragma unroll
    for (int kt = 0; kt < 4; ++kt)
      bfrw[kt] = *(const s16x8*)(wsW + 32768 + nrow * 128 + kt * 32 + kgrp);
    float bval = bv[nrow];
#pragma unroll
    for (int mt = 0; mt < 4; ++mt) {
      f32x4 acc = {0.f, 0.f, 0.f, 0.f};
#pragma unroll
      for (int kt = 0; kt < 4; ++kt) {
        s16x8 afr = *(const s16x8*)(sm + 32768 + swz256(mt * 16 + l15, (kt * 32 + kgrp) * 2));
        acc = MFMA16(afr, bfrw[kt], acc);
      }
      u32x2 w = {pk2(acc[0] + bval, acc[1] + bval), pk2(acc[2] + bval, acc[3] + bval)};
      *(u32x2*)(qkvimg + wb + 32768 + swz128(nrow, 2 * (mt * 16 + rsub))) = w;
    }
  }
}

// ================= K2: stage image via global_load_lds; attention + proj + scatter =================
__global__ __launch_bounds__(512, 6) void swin_attn(
    const char* __restrict__ qkvimg, const float* __restrict__ bp,
    const unsigned short* __restrict__ wsW, const float* __restrict__ rpbm,
    float* __restrict__ out) {
  __shared__ __align__(16) char sm[49152];   // Q [0,16K) -> O ; K [16K,32K) ; V^T [32K,48K)

  const int tid = threadIdx.x;
  const int lane = tid & 63;
  const int wv_ = tid >> 6;
  const int l15 = lane & 15;
  const int lg = lane >> 4;
  const int kgrp = lg * 8;
  const int rsub = lg * 4;
  const int l31 = lane & 31;
  const int hi = lane >> 5;

  const int bid = blockIdx.x;
  const int b = bid >> 6;
  const int widx = bid & 63;
  const int wi = widx >> 3, wj = widx & 7;
  const long obase = (long)b * 56 * 56 * 128;
  const int mcase = ((wi == 7) ? 2 : 0) + ((wj == 7) ? 1 : 0);

  // ---- stage: 6 DMA per wave, linear copy of the pre-swizzled image ----
  {
    const char* src = qkvimg + (long)bid * 49152 + wv_ * 6144 + lane * 16;
#pragma unroll
    for (int i = 0; i < 6; ++i)
      gload16(src + i * 1024, sm + wv_ * 6144 + i * 1024);
  }

  const int h = wv_ & 3;
  const int half = wv_ >> 2;
  const int coff = h * 32;

  // rpbm -> S init (L2-hot loads issued before the barrier)
  const float* rpbm_h = rpbm + (((mcase << 2) + h) << 12) + (half * 32 + l31) * 64 + 4 * hi;
  f32x16 S[2];
#pragma unroll
  for (int t = 0; t < 2; ++t)
#pragma unroll
    for (int g = 0; g < 4; ++g) {
      f32x4 rv = *(const f32x4*)(rpbm_h + t * 32 + g * 8);
      S[t][g*4+0] = rv[0]; S[t][g*4+1] = rv[1];
      S[t][g*4+2] = rv[2]; S[t][g*4+3] = rv[3];
    }
  __syncthreads();   // B1: image staged

  f32x16 O;
  {
    s16x8 qfr[2], kfr[2][2];
#pragma unroll
    for (int s = 0; s < 2; ++s) {
      qfr[s] = *(const s16x8*)(sm + swz256(half * 32 + l31, 2 * (coff + s * 16 + hi * 8)));
#pragma unroll
      for (int t = 0; t < 2; ++t)
        kfr[t][s] = *(const s16x8*)(sm + 16384 + swz256(t * 32 + l31, 2 * (coff + s * 16 + hi * 8)));
    }
#pragma unroll
    for (int s = 0; s < 2; ++s) {
      S[0] = MFMA32(kfr[0][s], qfr[s], S[0]);
      S[1] = MFMA32(kfr[1][s], qfr[s], S[1]);
    }
    float m = S[0][0];
#pragma unroll
    for (int t = 0; t < 2; ++t)
#pragma unroll
      for (int r = 0; r < 16; ++r) m = fmaxf(m, S[t][r]);
    m = fmaxf(m, __shfl_xor(m, 32));
    float sum = 0.f;
#pragma unroll
    for (int t = 0; t < 2; ++t)
#pragma unroll
      for (int r = 0; r < 16; ++r) { float e = exp2f(S[t][r] - m); S[t][r] = e; sum += e; }
    sum += __shfl_xor(sum, 32);
    float inv = 1.0f / sum;
    unsigned int pu[2][4][2];
#pragma unroll
    for (int t = 0; t < 2; ++t)
#pragma unroll
      for (int g = 0; g < 4; ++g) {
        pu[t][g][0] = pk2(S[t][g*4+0] * inv, S[t][g*4+1] * inv);
        pu[t][g][1] = pk2(S[t][g*4+2] * inv, S[t][g*4+3] * inv);
      }
    O = (f32x16)0.f;
#pragma unroll
    for (int s = 0; s < 4; ++s) {
      const int t = s >> 1, gb = (s & 1) * 2;
      unsigned int own0 = pu[t][gb + hi][0], own1 = pu[t][gb + hi][1];
      unsigned int po0 = __shfl_xor(pu[t][gb + 1 - hi][0], 32);
      unsigned int po1 = __shfl_xor(pu[t][gb + 1 - hi][1], 32);
      union { u32x4 u; s16x8 s; } pf;
      pf.u = hi ? (u32x4){po0, po1, own0, own1} : (u32x4){own0, own1, po0, po1};
      s16x8 vfr = *(const s16x8*)(sm + 32768 + swz128(coff + l31, 2 * (s * 16 + hi * 8)));
      O = MFMA32(vfr, pf.s, O);
    }
  }
  __syncthreads();   // B2: all Q/K/V reads done

#pragma unroll
  for (int g = 0; g < 4; ++g) {
    u32x2 w = {pk2(O[g*4+0], O[g*4+1]), pk2(O[g*4+2], O[g*4+3])};
    *(u32x2*)(sm + swz256(half * 32 + l31, 2 * (coff + g * 8 + 4 * hi))) = w;
  }
  __syncthreads();   // B3: O visible in r0

  {
    const int nrow = wv_ * 16 + l15;
    s16x8 afr[4];
#pragma unroll
    for (int kt = 0; kt < 4; ++kt)
      afr[kt] = *(const s16x8*)(wsW + 49152 + nrow * 128 + kt * 32 + kgrp);
    f32x4 bv4 = *(const f32x4*)(bp + wv_ * 16 + rsub);
#pragma unroll
    for (int tt = 0; tt < 4; ++tt) {
      f32x4 acc = {0.f, 0.f, 0.f, 0.f};
#pragma unroll
      for (int kt = 0; kt < 4; ++kt) {
        s16x8 bfr = *(const s16x8*)(sm + swz256(tt * 16 + l15, (kt * 32 + kgrp) * 2));
        acc = MFMA16(afr[kt], bfr, acc);
      }
      int tok = tt * 16 + l15;
      if (tok < 49) {
        int ty = div7(tok), tx = tok - ty * 7;
        int oh = wi * 7 + ty + 3; if (oh >= 56) oh -= 56;
        int ow = wj * 7 + tx + 3; if (ow >= 56) ow -= 56;
        f32x4 res = {acc[0] + bv4[0], acc[1] + bv4[1], acc[2] + bv4[2], acc[3] + bv4[3]};
        *(f32x4*)(out + obase + (oh * 56 + ow) * 128 + wv_ * 16 + rsub) = res;
      }
    }
  }
}

// ================= fallback: R7 single-kernel (known-good 82.9 us) =================
__global__ __launch_bounds__(512, 6) void swin_main(
    const float* __restrict__ xq, const float* __restrict__ xk, const float* __restrict__ xv,
    const float* __restrict__ bq, const float* __restrict__ bk, const float* __restrict__ bv,
    const float* __restrict__ bp, const unsigned short* __restrict__ wsW,
    const float* __restrict__ rpbm, float* __restrict__ out) {
  __shared__ __align__(16) char sm[49152];

  const int tid = threadIdx.x;
  const int lane = tid & 63;
  const int wv_ = tid >> 6;
  const int l15 = lane & 15;
  const int lg = lane >> 4;
  const int kgrp = lg * 8;
  const int rsub = lg * 4;
  const int l31 = lane & 31;
  const int hi = lane >> 5;

  const int bid = blockIdx.x;
  const int b = bid >> 6;
  const int widx = bid & 63;
  const int wi = widx >> 3, wj = widx & 7;
  const long obase = (long)b * 56 * 56 * 128;
  const int mcase = ((wi == 7) ? 2 : 0) + ((wj == 7) ? 1 : 0);

  const int xrow = tid >> 3;
  const int xk16 = (tid & 7) << 4;
  long xoff = -1;
  if (xrow < 49) {
    int ty = div7(xrow), tx = xrow - ty * 7;
    int ih = wi * 7 + ty + 3; if (ih >= 56) ih -= 56;
    int iw = wj * 7 + tx + 3; if (iw >= 56) iw -= 56;
    xoff = obase + (long)((ih * 56 + iw) * 128 + xk16);
  }
  {
    float ra[16], rb[16], rc[16];
#pragma unroll
    for (int i = 0; i < 16; ++i) { ra[i] = 0.f; rb[i] = 0.f; rc[i] = 0.f; }
    if (xoff >= 0) {
#pragma unroll
      for (int q = 0; q < 4; ++q) {
        f32x4 v = *(const f32x4*)(xq + xoff + q * 4);
        ra[q*4+0]=v[0]; ra[q*4+1]=v[1]; ra[q*4+2]=v[2]; ra[q*4+3]=v[3];
      }
#pragma unroll
      for (int q = 0; q < 4; ++q) {
        f32x4 v = *(const f32x4*)(xk + xoff + q * 4);
        rb[q*4+0]=v[0]; rb[q*4+1]=v[1]; rb[q*4+2]=v[2]; rb[q*4+3]=v[3];
      }
#pragma unroll
      for (int q = 0; q < 4; ++q) {
        f32x4 v = *(const f32x4*)(xv + xoff + q * 4);
        rc[q*4+0]=v[0]; rc[q*4+1]=v[1]; rc[q*4+2]=v[2]; rc[q*4+3]=v[3];
      }
    }
    auto wrx = [&](int base, const float* r) {
      unsigned int w[8];
#pragma unroll
      for (int i = 0; i < 8; ++i) w[i] = pk2(r[2*i], r[2*i+1]);
      u32x4 a = {w[0], w[1], w[2], w[3]};
      u32x4 bb2 = {w[4], w[5], w[6], w[7]};
      *(u32x4*)(sm + base + swz256(xrow, xk16 * 2)) = a;
      *(u32x4*)(sm + base + swz256(xrow, xk16 * 2 + 16)) = bb2;
    };
    wrx(0, ra); wrx(16384, rb); wrx(32768, rc);
  }
  __syncthreads();

  const float QSCALE = 0.17677669529663687f * LOG2E;
  unsigned int qpk[4][2], kpk[4][2], vpk[4][2];
  {
    const int nrow = wv_ * 16 + l15;
    {
      s16x8 afr[4];
#pragma unroll
      for (int kt = 0; kt < 4; ++kt)
        afr[kt] = *(const s16x8*)(wsW + nrow * 128 + kt * 32 + kgrp);
      f32x4 bv4 = *(const f32x4*)(bq + wv_ * 16 + rsub);
#pragma unroll
      for (int tt = 0; tt < 4; ++tt) {
        f32x4 acc = {0.f, 0.f, 0.f, 0.f};
#pragma unroll
        for (int kt = 0; kt < 4; ++kt) {
          s16x8 bfr = *(const s16x8*)(sm + swz256(tt * 16 + l15, (kt * 32 + kgrp) * 2));
          acc = MFMA16(afr[kt], bfr, acc);
        }
        qpk[tt][0] = pk2((acc[0] + bv4[0]) * QSCALE, (acc[1] + bv4[1]) * QSCALE);
        qpk[tt][1] = pk2((acc[2] + bv4[2]) * QSCALE, (acc[3] + bv4[3]) * QSCALE);
      }
    }
    {
      s16x8 afr[4];
#pragma unroll
      for (int kt = 0; kt < 4; ++kt)
        afr[kt] = *(const s16x8*)(wsW + 16384 + nrow * 128 + kt * 32 + kgrp);
      f32x4 bv4 = *(const f32x4*)(bk + wv_ * 16 + rsub);
#pragma unroll
      for (int tt = 0; tt < 4; ++tt) {
        f32x4 acc = {0.f, 0.f, 0.f, 0.f};
#pragma unroll
        for (int kt = 0; kt < 4; ++kt) {
          s16x8 bfr = *(const s16x8*)(sm + 16384 + swz256(tt * 16 + l15, (kt * 32 + kgrp) * 2));
          acc = MFMA16(afr[kt], bfr, acc);
        }
        kpk[tt][0] = pk2(acc[0] + bv4[0], acc[1] + bv4[1]);
        kpk[tt][1] = pk2(acc[2] + bv4[2], acc[3] + bv4[3]);
      }
    }
    {
      s16x8 bfrw[4];
#pragma unroll
      for (int kt = 0; kt < 4; ++kt)
        bfrw[kt] = *(const s16x8*)(wsW + 32768 + nrow * 128 + kt * 32 + kgrp);
      float bval = bv[nrow];
#pragma unroll
      for (int mt = 0; mt < 4; ++mt) {
        f32x4 acc = {0.f, 0.f, 0.f, 0.f};
#pragma unroll
        for (int kt = 0; kt < 4; ++kt) {
          s16x8 afr = *(const s16x8*)(sm + 32768 + swz256(mt * 16 + l15, (kt * 32 + kgrp) * 2));
          acc = MFMA16(afr, bfrw[kt], acc);
        }
        vpk[mt][0] = pk2(acc[0] + bval, acc[1] + bval);
        vpk[mt][1] = pk2(acc[2] + bval, acc[3] + bval);
      }
    }
  }
  __syncthreads();

#pragma unroll
  for (int tt = 0; tt < 4; ++tt) {
    u32x2 w = {qpk[tt][0], qpk[tt][1]};
    *(u32x2*)(sm + swz256(tt * 16 + l15, 2 * (wv_ * 16 + rsub))) = w;
  }
#pragma unroll
  for (int tt = 0; tt < 4; ++tt) {
    u32x2 w = {kpk[tt][0], kpk[tt][1]};
    *(u32x2*)(sm + 16384 + swz256(tt * 16 + l15, 2 * (wv_ * 16 + rsub))) = w;
  }
#pragma unroll
  for (int mt = 0; mt < 4; ++mt) {
    u32x2 w = {vpk[mt][0], vpk[mt][1]};
    *(u32x2*)(sm + 32768 + swz128(wv_ * 16 + l15, 2 * (mt * 16 + rsub))) = w;
  }
  __syncthreads();

  const int h = wv_ & 3;
  const int half = wv_ >> 2;
  const int coff = h * 32;
  f32x16 O;
  {
    const float* rpbm_h = rpbm + (((mcase << 2) + h) << 12) + (half * 32 + l31) * 64 + 4 * hi;
    f32x16 S[2];
#pragma unroll
    for (int t = 0; t < 2; ++t)
#pragma unroll
      for (int g = 0; g < 4; ++g) {
        f32x4 rv = *(const f32x4*)(rpbm_h + t * 32 + g * 8);
        S[t][g*4+0] = rv[0]; S[t][g*4+1] = rv[1];
        S[t][g*4+2] = rv[2]; S[t][g*4+3] = rv[3];
      }
    s16x8 qfr[2], kfr[2][2];
#pragma unroll
    for (int s = 0; s < 2; ++s) {
      qfr[s] = *(const s16x8*)(sm + swz256(half * 32 + l31, 2 * (coff + s * 16 + hi * 8)));
#pragma unroll
      for (int t = 0; t < 2; ++t)
        kfr[t][s] = *(const s16x8*)(sm + 16384 + swz256(t * 32 + l31, 2 * (coff + s * 16 + hi * 8)));
    }
#pragma unroll
    for (int s = 0; s < 2; ++s) {
      S[0] = MFMA32(kfr[0][s], qfr[s], S[0]);
      S[1] = MFMA32(kfr[1][s], qfr[s], S[1]);
    }
    float m = S[0][0];
#pragma unroll
    for (int t = 0; t < 2; ++t)
#pragma unroll
      for (int r = 0; r < 16; ++r) m = fmaxf(m, S[t][r]);
    m = fmaxf(m, __shfl_xor(m, 32));
    float sum = 0.f;
#pragma unroll
    for (int t = 0; t < 2; ++t)
#pragma unroll
      for (int r = 0; r < 16; ++r) { float e = exp2f(S[t][r] - m); S[t][r] = e; sum += e; }
    sum += __shfl_xor(sum, 32);
    float inv = 1.0f / sum;
    unsigned int pu[2][4][2];
#pragma unroll
    for (int t = 0; t < 2; ++t)
#pragma unroll
      for (int g = 0; g < 4; ++g) {
        pu[t][g][0] = pk2(S[t][g*4+0] * inv, S[t][g*4+1] * inv);
        pu[t][g][1] = pk2(S[t][g*4+2] * inv, S[t][g*4+3] * inv);
      }
    O = (f32x16)0.f;
#pragma unroll
    for (int s = 0; s < 4; ++s) {
      const int t = s >> 1, gb = (s & 1) * 2;
      unsigned int own0 = pu[t][gb + hi][0], own1 = pu[t][gb + hi][1];
      unsigned int po0 = __shfl_xor(pu[t][gb + 1 - hi][0], 32);
      unsigned int po1 = __shfl_xor(pu[t][gb + 1 - hi][1], 32);
      union { u32x4 u; s16x8 s; } pf;
      pf.u = hi ? (u32x4){po0, po1, own0, own1} : (u32x4){own0, own1, po0, po1};
      s16x8 vfr = *(const s16x8*)(sm + 32768 + swz128(coff + l31, 2 * (s * 16 + hi * 8)));
      O = MFMA32(vfr, pf.s, O);
    }
  }
  __syncthreads();

#pragma unroll
  for (int g = 0; g < 4; ++g) {
    u32x2 w = {pk2(O[g*4+0], O[g*4+1]), pk2(O[g*4+2], O[g*4+3])};
    *(u32x2*)(sm + swz256(half * 32 + l31, 2 * (coff + g * 8 + 4 * hi))) = w;
  }
  __syncthreads();

  {
    const int nrow = wv_ * 16 + l15;
    s16x8 afr[4];
#pragma unroll
    for (int kt = 0; kt < 4; ++kt)
      afr[kt] = *(const s16x8*)(wsW + 49152 + nrow * 128 + kt * 32 + kgrp);
    f32x4 bv4 = *(const f32x4*)(bp + wv_ * 16 + rsub);
#pragma unroll
    for (int tt = 0; tt < 4; ++tt) {
      f32x4 acc = {0.f, 0.f, 0.f, 0.f};
#pragma unroll
      for (int kt = 0; kt < 4; ++kt) {
        s16x8 bfr = *(const s16x8*)(sm + swz256(tt * 16 + l15, (kt * 32 + kgrp) * 2));
        acc = MFMA16(afr[kt], bfr, acc);
      }
      int tok = tt * 16 + l15;
      if (tok < 49) {
        int ty = div7(tok), tx = tok - ty * 7;
        int oh = wi * 7 + ty + 3; if (oh >= 56) oh -= 56;
        int ow = wj * 7 + tx + 3; if (ow >= 56) ow -= 56;
        f32x4 res = {acc[0] + bv4[0], acc[1] + bv4[1], acc[2] + bv4[2], acc[3] + bv4[3]};
        *(f32x4*)(out + obase + (oh * 56 + ow) * 128 + wv_ * 16 + rsub) = res;
      }
    }
  }
}

extern "C" void kernel_launch(void* const* d_in, const int* in_sizes, int n_in,
                              void* d_out, int out_size, void* d_ws, size_t ws_size,
                              hipStream_t stream) {
  const float* xq = (const float*)d_in[0];
  const float* xk = (const float*)d_in[1];
  const float* xv = (const float*)d_in[2];
  const float* wq = (const float*)d_in[3];
  const float* bq = (const float*)d_in[4];
  const float* wk = (const float*)d_in[5];
  const float* bk = (const float*)d_in[6];
  const float* wv = (const float*)d_in[7];
  const float* bv = (const float*)d_in[8];
  const float* wp = (const float*)d_in[9];
  const float* bp = (const float*)d_in[10];
  const float* rpb = (const float*)d_in[11];

  unsigned short* wsW = (unsigned short*)d_ws;          // 128 KB
  float* rpbm = (float*)((char*)d_ws + 131072);         // 256 KB
  char* qkvimg = (char*)d_ws + 393216;                  // 2048 * 48 KB = 100.66 MB
  const size_t NEED = 393216ull + 2048ull * 49152ull;

  swin_prep<<<512, 256, 0, stream>>>(wq, wk, wv, wp, rpb, wsW, rpbm);

  float* out = (float*)d_out;
  if (ws_size >= NEED) {
    swin_qkv<<<2048, 512, 0, stream>>>(xq, xk, xv, bq, bk, bv, wsW, qkvimg);
    swin_attn<<<2048, 512, 0, stream>>>(qkvimg, bp, wsW, rpbm, out);
  } else {
    swin_main<<<2048, 512, 0, stream>>>(xq, xk, xv, bq, bk, bv, bp, wsW, rpbm, out);
  }
}

// Round 10
// 89.781 us; speedup vs baseline: 1.4747x; 1.4747x over previous
//
#include <hip/hip_runtime.h>
#include <hip/hip_bf16.h>

typedef __attribute__((ext_vector_type(8))) short s16x8;
typedef __attribute__((ext_vector_type(4))) float f32x4;
typedef __attribute__((ext_vector_type(16))) float f32x16;
typedef __attribute__((ext_vector_type(2))) unsigned int u32x2;
typedef __attribute__((ext_vector_type(4))) unsigned int u32x4;

#define MFMA16(a, b, c) __builtin_amdgcn_mfma_f32_16x16x32_bf16((a), (b), (c), 0, 0, 0)
#define MFMA32(a, b, c) __builtin_amdgcn_mfma_f32_32x32x16_bf16((a), (b), (c), 0, 0, 0)
#define LOG2E 1.4426950408889634f

static __device__ __forceinline__ unsigned int pk2(float a, float b) {
  union { __hip_bfloat162 h2; unsigned int u; } cv;
  cv.h2 = __float22bfloat162_rn(make_float2(a, b));
  return cv.u;
}
static __device__ __forceinline__ int div7(int x) { return (x * 9363) >> 16; }  // exact 0..62
static __device__ __forceinline__ int swz256(int row, int byteoff) {
  return row * 256 + (byteoff ^ ((row & 7) << 4));
}
static __device__ __forceinline__ int swz128(int row, int byteoff) {
  return row * 128 + (byteoff ^ ((row & 7) << 4));
}
static __device__ __forceinline__ void gload16(const void* g, void* l) {
  __builtin_amdgcn_global_load_lds(
      (const __attribute__((address_space(1))) unsigned int*)g,
      (__attribute__((address_space(3))) unsigned int*)l, 16, 0, 0);
}

// ---------- prep: weights fp32->bf16 ; rpbm[case][head][64][64] = (rpb + mask)*log2e ----------
__global__ void swin_prep(const float* __restrict__ wq, const float* __restrict__ wk,
                          const float* __restrict__ wv, const float* __restrict__ wp,
                          const float* __restrict__ rpb_table,
                          unsigned short* __restrict__ wsW, float* __restrict__ rpbm) {
  int idx = blockIdx.x * 256 + threadIdx.x;
  if (idx < 65536) {
    int t = idx >> 14, loc = idx & 16383;
    const float* s = (t == 0) ? wq : (t == 1) ? wk : (t == 2) ? wv : wp;
    union { __hip_bfloat16 h; unsigned short u; } cv;
    cv.h = __float2bfloat16(s[loc]);
    wsW[idx] = cv.u;
  } else {
    int k = idx - 65536;               // [case(2b)][head(2b)][i(6b)][j(6b)]
    int c = k >> 14;
    int h = (k >> 12) & 3;
    int i = (k >> 6) & 63, j = k & 63;
    float val;
    if (j >= 49) val = -1e30f;
    else if (i >= 49) val = 0.f;
    else {
      int yi = div7(i), xi = i - yi * 7;
      int yj = div7(j), xj = j - yj * 7;
      int ridx = (yi - yj + 6) * 13 + (xi - xj + 6);
      val = rpb_table[ridx * 4 + h];
      int cwi = c >> 1, cwj = c & 1;
      int rgi = (cwi ? (yi < 4 ? 3 : 6) : 0) + (cwj ? (xi < 4 ? 1 : 2) : 0);
      int rgj = (cwi ? (yj < 4 ? 3 : 6) : 0) + (cwj ? (xj < 4 ? 1 : 2) : 0);
      if (rgi != rgj) val -= 100.f;
      val *= LOG2E;
    }
    rpbm[k] = val;
  }
}

// ---------- main: one 512-thread WG per (batch, window); DMA-staged front-end ----------
// LDS: F = [0,32K) fp32 X stage (linear [64 tok][128 ch]); R2 = [32K,48K) bf16 X -> V^T.
// After staging phase: Q -> [0,16K) (R0), K -> [16K,32K) (R1); O -> R0; proj from R0.
__global__ __launch_bounds__(512, 6) void swin_main(
    const float* __restrict__ xq, const float* __restrict__ xk, const float* __restrict__ xv,
    const float* __restrict__ bq, const float* __restrict__ bk, const float* __restrict__ bv,
    const float* __restrict__ bp, const unsigned short* __restrict__ wsW,
    const float* __restrict__ rpbm, float* __restrict__ out) {
  __shared__ __align__(16) char sm[49152];

  const int tid = threadIdx.x;
  const int lane = tid & 63;
  const int wv_ = tid >> 6;       // wave 0..7
  const int l15 = lane & 15;
  const int lg = lane >> 4;
  const int kgrp = lg * 8;
  const int rsub = lg * 4;
  const int l31 = lane & 31;
  const int hi = lane >> 5;

  const int bid = blockIdx.x;
  const int b = bid >> 6;
  const int widx = bid & 63;
  const int wi = widx >> 3, wj = widx & 7;
  const long obase = (long)b * 56 * 56 * 128;
  const int mcase = ((wi == 7) ? 2 : 0) + ((wj == 7) ? 1 : 0);

  // ---- DMA source offsets: DMA i of wave wv_ covers toks wv_*8+i*2+hi, chunk l31 ----
  // LDS dest (linear F): wv_*4096 + i*1024 (+ lane*16 implicit). 4 DMAs/thread = 32 KB.
  long dsrc[4];
#pragma unroll
  for (int i = 0; i < 4; ++i) {
    int tok = wv_ * 8 + i * 2 + hi;
    long off = 0;
    if (tok < 49) {
      int ty = div7(tok), tx = tok - ty * 7;
      int ih = wi * 7 + ty + 3; if (ih >= 56) ih -= 56;
      int iw = wj * 7 + tx + 3; if (iw >= 56) iw -= 56;
      off = (long)(ih * 56 + iw) * 512;
    }
    dsrc[i] = obase * 4 + off + (long)l31 * 16;   // bytes
  }
  auto dma_x = [&](const float* src) {
    const char* s8 = (const char*)src;
#pragma unroll
    for (int i = 0; i < 4; ++i)
      gload16(s8 + dsrc[i], sm + wv_ * 4096 + i * 1024);
  };

  // ---- cvt pass: F (fp32 linear) -> R2 (bf16 swizzled); rows >=49 zeroed ----
  const int ctok = tid >> 3;
  const int cch16 = (tid & 7) << 4;
  auto cvt_x = [&]() {
    u32x4 a, bb;
    if (ctok < 49) {
      const char* fp = sm + ctok * 512 + (tid & 7) * 64;
      f32x4 v0 = *(const f32x4*)(fp);
      f32x4 v1 = *(const f32x4*)(fp + 16);
      f32x4 v2 = *(const f32x4*)(fp + 32);
      f32x4 v3 = *(const f32x4*)(fp + 48);
      a = (u32x4){pk2(v0[0], v0[1]), pk2(v0[2], v0[3]), pk2(v1[0], v1[1]), pk2(v1[2], v1[3])};
      bb = (u32x4){pk2(v2[0], v2[1]), pk2(v2[2], v2[3]), pk2(v3[0], v3[1]), pk2(v3[2], v3[3])};
    } else {
      a = (u32x4){0, 0, 0, 0};
      bb = (u32x4){0, 0, 0, 0};
    }
    *(u32x4*)(sm + 32768 + swz256(ctok, cch16 * 2)) = a;
    *(u32x4*)(sm + 32768 + swz256(ctok, cch16 * 2 + 16)) = bb;
  };

  const float QSCALE = 0.17677669529663687f * LOG2E;
  const int nrow = wv_ * 16 + l15;

  // ---- GEMM from bf16 X in R2 (base 32768): D[n][tok] = mfma16(A=W, B=X) -> packed regs ----
  unsigned int qpk[4][2], kpk[4][2], vpk[4][2];
  auto gemmT = [&](int woff, const float* bias, float scale, unsigned int dst[4][2]) {
    s16x8 afr[4];
#pragma unroll
    for (int kt = 0; kt < 4; ++kt)
      afr[kt] = *(const s16x8*)(wsW + woff + nrow * 128 + kt * 32 + kgrp);
    f32x4 bv4 = *(const f32x4*)(bias + wv_ * 16 + rsub);
#pragma unroll
    for (int tt = 0; tt < 4; ++tt) {
      f32x4 acc = {0.f, 0.f, 0.f, 0.f};
#pragma unroll
      for (int kt = 0; kt < 4; ++kt) {
        s16x8 bfr = *(const s16x8*)(sm + 32768 + swz256(tt * 16 + l15, (kt * 32 + kgrp) * 2));
        acc = MFMA16(afr[kt], bfr, acc);
      }
      dst[tt][0] = pk2((acc[0] + bv4[0]) * scale, (acc[1] + bv4[1]) * scale);
      dst[tt][1] = pk2((acc[2] + bv4[2]) * scale, (acc[3] + bv4[3]) * scale);
    }
  };
  // V: D[tok][n] = mfma16(A=X, B=W), lane = ch
  auto gemmV = [&](int woff, const float* bias) {
    s16x8 bfrw[4];
#pragma unroll
    for (int kt = 0; kt < 4; ++kt)
      bfrw[kt] = *(const s16x8*)(wsW + woff + nrow * 128 + kt * 32 + kgrp);
    float bval = bias[nrow];
#pragma unroll
    for (int mt = 0; mt < 4; ++mt) {
      f32x4 acc = {0.f, 0.f, 0.f, 0.f};
#pragma unroll
      for (int kt = 0; kt < 4; ++kt) {
        s16x8 afr = *(const s16x8*)(sm + 32768 + swz256(mt * 16 + l15, (kt * 32 + kgrp) * 2));
        acc = MFMA16(afr, bfrw[kt], acc);
      }
      vpk[mt][0] = pk2(acc[0] + bval, acc[1] + bval);
      vpk[mt][1] = pk2(acc[2] + bval, acc[3] + bval);
    }
  };

  // ================= pipeline =================
  dma_x(xq);
  __syncthreads();                           // B1: Xq fp32 in F
  cvt_x();
  __syncthreads();                           // B2: bf16 Xq in R2
  dma_x(xk);                                 // Xk -> F (overlaps GEMM-Q)
  gemmT(0, bq, QSCALE, qpk);
  __syncthreads();                           // B3: Xk landed; Q in regs
  cvt_x();
  __syncthreads();                           // B4: bf16 Xk in R2
  dma_x(xv);
  gemmT(16384, bk, 1.f, kpk);
  __syncthreads();                           // B5: Xv landed; K in regs
  cvt_x();
  __syncthreads();                           // B6: bf16 Xv in R2; F dead
  // GEMM-V (reads R2) || write Q->R0, K->R1 (F region, dead)
  gemmV(32768, bv);
#pragma unroll
  for (int tt = 0; tt < 4; ++tt) {
    u32x2 w = {qpk[tt][0], qpk[tt][1]};
    *(u32x2*)(sm + swz256(tt * 16 + l15, 2 * (wv_ * 16 + rsub))) = w;
  }
#pragma unroll
  for (int tt = 0; tt < 4; ++tt) {
    u32x2 w = {kpk[tt][0], kpk[tt][1]};
    *(u32x2*)(sm + 16384 + swz256(tt * 16 + l15, 2 * (wv_ * 16 + rsub))) = w;
  }
  __syncthreads();                           // B7: Q,K staged; R2 reads done

  // ---- phase 8: write V^T -> R2  ||  QK^T + softmax -> P-regs ----
  const int h = wv_ & 3;
  const int half = wv_ >> 2;
  const int coff = h * 32;
  unsigned int pu[2][4][2];
  {
#pragma unroll
    for (int mt = 0; mt < 4; ++mt) {
      u32x2 w = {vpk[mt][0], vpk[mt][1]};
      *(u32x2*)(sm + 32768 + swz128(wv_ * 16 + l15, 2 * (mt * 16 + rsub))) = w;
    }
    const float* rpbm_h = rpbm + (((mcase << 2) + h) << 12) + (half * 32 + l31) * 64 + 4 * hi;
    f32x16 S[2];
#pragma unroll
    for (int t = 0; t < 2; ++t)
#pragma unroll
      for (int g = 0; g < 4; ++g) {
        f32x4 rv = *(const f32x4*)(rpbm_h + t * 32 + g * 8);
        S[t][g*4+0] = rv[0]; S[t][g*4+1] = rv[1];
        S[t][g*4+2] = rv[2]; S[t][g*4+3] = rv[3];
      }
    s16x8 qfr[2], kfr[2][2];
#pragma unroll
    for (int s = 0; s < 2; ++s) {
      qfr[s] = *(const s16x8*)(sm + swz256(half * 32 + l31, 2 * (coff + s * 16 + hi * 8)));
#pragma unroll
      for (int t = 0; t < 2; ++t)
        kfr[t][s] = *(const s16x8*)(sm + 16384 + swz256(t * 32 + l31, 2 * (coff + s * 16 + hi * 8)));
    }
#pragma unroll
    for (int s = 0; s < 2; ++s) {
      S[0] = MFMA32(kfr[0][s], qfr[s], S[0]);
      S[1] = MFMA32(kfr[1][s], qfr[s], S[1]);
    }
    float m = S[0][0];
#pragma unroll
    for (int t = 0; t < 2; ++t)
#pragma unroll
      for (int r = 0; r < 16; ++r) m = fmaxf(m, S[t][r]);
    m = fmaxf(m, __shfl_xor(m, 32));
    float sum = 0.f;
#pragma unroll
    for (int t = 0; t < 2; ++t)
#pragma unroll
      for (int r = 0; r < 16; ++r) { float e = exp2f(S[t][r] - m); S[t][r] = e; sum += e; }
    sum += __shfl_xor(sum, 32);
    float inv = 1.0f / sum;
#pragma unroll
    for (int t = 0; t < 2; ++t)
#pragma unroll
      for (int g = 0; g < 4; ++g) {
        pu[t][g][0] = pk2(S[t][g*4+0] * inv, S[t][g*4+1] * inv);
        pu[t][g][1] = pk2(S[t][g*4+2] * inv, S[t][g*4+3] * inv);
      }
  }
  __syncthreads();                           // B8: V^T staged; Q/K reads done

  // ---- phase 9: PV + write O -> R0 ----
  {
    f32x16 O = (f32x16)0.f;
#pragma unroll
    for (int s = 0; s < 4; ++s) {
      const int t = s >> 1, gb = (s & 1) * 2;
      unsigned int own0 = pu[t][gb + hi][0], own1 = pu[t][gb + hi][1];
      unsigned int po0 = __shfl_xor(pu[t][gb + 1 - hi][0], 32);
      unsigned int po1 = __shfl_xor(pu[t][gb + 1 - hi][1], 32);
      union { u32x4 u; s16x8 s; } pf;
      pf.u = hi ? (u32x4){po0, po1, own0, own1} : (u32x4){own0, own1, po0, po1};
      s16x8 vfr = *(const s16x8*)(sm + 32768 + swz128(coff + l31, 2 * (s * 16 + hi * 8)));
      O = MFMA32(vfr, pf.s, O);
    }
#pragma unroll
    for (int g = 0; g < 4; ++g) {
      u32x2 w = {pk2(O[g*4+0], O[g*4+1]), pk2(O[g*4+2], O[g*4+3])};
      *(u32x2*)(sm + swz256(half * 32 + l31, 2 * (coff + g * 8 + 4 * hi))) = w;
    }
  }
  __syncthreads();                           // B9: O in R0

  // ---- phase 10: proj + rolled scatter ----
  {
    s16x8 afr[4];
#pragma unroll
    for (int kt = 0; kt < 4; ++kt)
      afr[kt] = *(const s16x8*)(wsW + 49152 + nrow * 128 + kt * 32 + kgrp);
    f32x4 bv4 = *(const f32x4*)(bp + wv_ * 16 + rsub);
#pragma unroll
    for (int tt = 0; tt < 4; ++tt) {
      f32x4 acc = {0.f, 0.f, 0.f, 0.f};
#pragma unroll
      for (int kt = 0; kt < 4; ++kt) {
        s16x8 bfr = *(const s16x8*)(sm + swz256(tt * 16 + l15, (kt * 32 + kgrp) * 2));
        acc = MFMA16(afr[kt], bfr, acc);
      }
      int tok = tt * 16 + l15;
      if (tok < 49) {
        int ty = div7(tok), tx = tok - ty * 7;
        int oh = wi * 7 + ty + 3; if (oh >= 56) oh -= 56;
        int ow = wj * 7 + tx + 3; if (ow >= 56) ow -= 56;
        f32x4 res = {acc[0] + bv4[0], acc[1] + bv4[1], acc[2] + bv4[2], acc[3] + bv4[3]};
        *(f32x4*)(out + obase + (oh * 56 + ow) * 128 + wv_ * 16 + rsub) = res;
      }
    }
  }
}

extern "C" void kernel_launch(void* const* d_in, const int* in_sizes, int n_in,
                              void* d_out, int out_size, void* d_ws, size_t ws_size,
                              hipStream_t stream) {
  const float* xq = (const float*)d_in[0];
  const float* xk = (const float*)d_in[1];
  const float* xv = (const float*)d_in[2];
  const float* wq = (const float*)d_in[3];
  const float* bq = (const float*)d_in[4];
  const float* wk = (const float*)d_in[5];
  const float* bk = (const float*)d_in[6];
  const float* wv = (const float*)d_in[7];
  const float* bv = (const float*)d_in[8];
  const float* wp = (const float*)d_in[9];
  const float* bp = (const float*)d_in[10];
  const float* rpb = (const float*)d_in[11];

  unsigned short* wsW = (unsigned short*)d_ws;          // 128 KB
  float* rpbm = (float*)((char*)d_ws + 131072);         // 256 KB

  swin_prep<<<512, 256, 0, stream>>>(wq, wk, wv, wp, rpb, wsW, rpbm);

  float* out = (float*)d_out;
  swin_main<<<2048, 512, 0, stream>>>(xq, xk, xv, bq, bk, bv, bp, wsW, rpbm, out);
}